// Round 15
// baseline (3287.985 us; speedup 1.0000x reference)
//
#include <hip/hip_runtime.h>
#include <hip/hip_bf16.h>
#include <math.h>

#define NN   20000
#define NE   320000
#define TT   24
#define SDIM 16
#define DDIM 8
#define HID  128
#define HEADS 4
#define DPH  32
#define NL   3
#define TC   4          // timesteps batched per GNN chunk (divides TT)

typedef unsigned short u16;
typedef unsigned int   u32;
typedef unsigned long long u64;
typedef __attribute__((ext_vector_type(8))) short  short8;
typedef __attribute__((ext_vector_type(4))) float  floatx4;

__device__ __forceinline__ u16 f2bf(float x) {          // round-to-nearest-even
  u32 u = __float_as_uint(x);
  return (u16)((u + 0x7fff + ((u >> 16) & 1)) >> 16);
}
__device__ __forceinline__ float bf2f(u16 b) {
  return __uint_as_float(((u32)b) << 16);
}

// ---------------- CSR build (group edges by dst) ----------------
__global__ void k_count(const int* __restrict__ dst, int* __restrict__ cnt) {
  int e = blockIdx.x * 256 + threadIdx.x;
  if (e < NE) atomicAdd(&cnt[dst[e]], 1);
}

__global__ __launch_bounds__(1024) void k_scan(const int* __restrict__ cnt,
    int* __restrict__ rowptr, int* __restrict__ cursor) {
  __shared__ int sh[1024];
  int tid = threadIdx.x;
  const int CH = 20;                      // 1024*20 >= NN
  int base = tid * CH;
  int local[CH];
  int s = 0;
  #pragma unroll
  for (int i = 0; i < CH; i++) {
    int idx = base + i;
    int v = (idx < NN) ? cnt[idx] : 0;
    local[i] = s;
    s += v;
  }
  sh[tid] = s;
  __syncthreads();
  for (int off = 1; off < 1024; off <<= 1) {
    int tv = (tid >= off) ? sh[tid - off] : 0;
    __syncthreads();
    sh[tid] += tv;
    __syncthreads();
  }
  int pre = (tid > 0) ? sh[tid - 1] : 0;
  #pragma unroll
  for (int i = 0; i < CH; i++) {
    int idx = base + i;
    if (idx < NN) { int e = pre + local[i]; rowptr[idx] = e; cursor[idx] = e; }
  }
  if (tid == 1023) rowptr[NN] = sh[1023];
}

__global__ void k_fill(const int* __restrict__ src, const int* __restrict__ dst,
    int* __restrict__ cursor, int* __restrict__ col, int* __restrict__ row) {
  int e = blockIdx.x * 256 + threadIdx.x;
  if (e < NE) {
    int d = dst[e];
    int pos = atomicAdd(&cursor[d], 1);
    col[pos] = src[e];
    row[pos] = d;
  }
}

// ---------------- weight prep ----------------
// LSTM weights, GATE-INTERLEAVED: Bt[4c+g][k] = W[g*128+c][k], W = [Wih | Whh]
__global__ void k_prepw_lstm(const float* __restrict__ Wih, const float* __restrict__ Whh,
    u16* __restrict__ Bt) {
  int idx = blockIdx.x * 256 + threadIdx.x;
  if (idx < 512 * 256) {
    int jp = idx >> 8, k = idx & 255;
    int c = jp >> 2, g = jp & 3;
    int j = g * 128 + c;
    float v = (k < 128) ? Wih[(size_t)j * 128 + k] : Whh[(size_t)j * 128 + (k - 128)];
    Bt[idx] = f2bf(v);
  }
}
// combined bias, gate-interleaved: bs[4c+g] = bih[g*128+c] + bhh[g*128+c]; 2 cells
__global__ void k_prepb(const float* __restrict__ bih0, const float* __restrict__ bhh0,
    const float* __restrict__ bih1, const float* __restrict__ bhh1,
    float* __restrict__ bs01) {
  int t = threadIdx.x;               // 512 per block, blockIdx.x = cell
  const float* bih = blockIdx.x ? bih1 : bih0;
  const float* bhh = blockIdx.x ? bhh1 : bhh0;
  int c = t >> 2, g = t & 3;
  bs01[blockIdx.x * 512 + t] = bih[g * 128 + c] + bhh[g * 128 + c];
}
// GAT: Btg[l][n][k] = gatW[l][k][n]
__global__ void k_prepw_gat(const float* __restrict__ gatW, u16* __restrict__ Btg) {
  int idx = blockIdx.x * 256 + threadIdx.x;
  if (idx < NL * 128 * 128) {
    int l = idx >> 14, r = idx & 16383;
    int n = r >> 7, k = r & 127;
    Btg[idx] = f2bf(gatW[(size_t)l * 16384 + k * 128 + n]);
  }
}

// ---------------- input projection (TC timesteps) ----------------
__global__ __launch_bounds__(256) void k_proj(const float* __restrict__ xs,
    const float* __restrict__ xdt, const float* __restrict__ W,
    const float* __restrict__ b, u16* __restrict__ hbf) {
  __shared__ float Ws[24 * HID];
  __shared__ float xin[16][24];
  int tid = threadIdx.x;
  int tc = blockIdx.y;
  for (int i = tid; i < 24 * HID; i += 256) Ws[i] = W[i];
  int n0 = blockIdx.x * 16;
  for (int i = tid; i < 16 * 24; i += 256) {
    int r = i / 24, c = i % 24;
    int n = n0 + r;
    xin[r][c] = (c < SDIM) ? xs[(size_t)n * SDIM + c]
                           : xdt[(size_t)tc * NN * DDIM + (size_t)n * DDIM + (c - SDIM)];
  }
  __syncthreads();
  int ch = tid & 127, rb = (tid >> 7) * 8;
  for (int r = rb; r < rb + 8; r++) {
    float acc = b[ch];
    #pragma unroll
    for (int k = 0; k < 24; k++) acc = fmaf(xin[r][k], Ws[k * HID + ch], acc);
    hbf[((size_t)tc * NN + n0 + r) * HID + ch] = f2bf(acc);
  }
}

#define TBM 128
#define TBN 64
#define TBK 64

// ---------------- GAT GEMM + fused attention-logit epilogue ----------------
__global__ __launch_bounds__(256) void k_bgemm_gat(const u16* __restrict__ A,
    const u16* __restrict__ Bt, const float* __restrict__ as_,
    const float* __restrict__ ad_, u16* __restrict__ xpbf,
    float* __restrict__ asrc, float* __restrict__ adst, int M) {
  __shared__ u16 As[TBM][TBK + 8];
  __shared__ u16 Bs[TBN][TBK + 8];
  int tid = threadIdx.x;
  int wid = tid >> 6, lane = tid & 63;
  int wr = wid >> 1, wc = wid & 1;
  int lrow = lane & 15, lgrp = lane >> 4;
  int row0 = blockIdx.x * TBM, col0 = blockIdx.y * TBN;
  floatx4 acc[4][2] = {};
  for (int k0 = 0; k0 < 128; k0 += TBK) {
    #pragma unroll
    for (int i = 0; i < 4; i++) {
      int idx = tid + i * 256;
      int r = idx >> 3, g = idx & 7;
      int gr = row0 + r;
      short8 v = {};
      if (gr < M) v = *(const short8*)(A + (size_t)gr * 128 + k0 + g * 8);
      *(short8*)&As[r][g * 8] = v;
    }
    #pragma unroll
    for (int i = 0; i < 2; i++) {
      int idx = tid + i * 256;
      int r = idx >> 3, g = idx & 7;
      *(short8*)&Bs[r][g * 8] = *(const short8*)(Bt + (size_t)(col0 + r) * 128 + k0 + g * 8);
    }
    __syncthreads();
    #pragma unroll
    for (int kk = 0; kk < TBK; kk += 32) {
      short8 bfr[2];
      #pragma unroll
      for (int n = 0; n < 2; n++)
        bfr[n] = *(const short8*)&Bs[wc * 32 + n * 16 + lrow][kk + lgrp * 8];
      #pragma unroll
      for (int m = 0; m < 4; m++) {
        short8 af = *(const short8*)&As[wr * 64 + m * 16 + lrow][kk + lgrp * 8];
        acc[m][0] = __builtin_amdgcn_mfma_f32_16x16x32_bf16(af, bfr[0], acc[m][0], 0, 0, 0);
        acc[m][1] = __builtin_amdgcn_mfma_f32_16x16x32_bf16(af, bfr[1], acc[m][1], 0, 0, 0);
      }
    }
    __syncthreads();
  }
  int head = (col0 >> 5) + wc;
  float as0 = as_[head * 32 + lrow], as1 = as_[head * 32 + 16 + lrow];
  float ad0 = ad_[head * 32 + lrow], ad1 = ad_[head * 32 + 16 + lrow];
  #pragma unroll
  for (int m = 0; m < 4; m++) {
    #pragma unroll
    for (int r = 0; r < 4; r++) {
      int grow = row0 + wr * 64 + m * 16 + lgrp * 4 + r;
      float v0 = acc[m][0][r], v1 = acc[m][1][r];
      if (grow < M) {
        xpbf[(size_t)grow * HID + col0 + wc * 32 + lrow]      = f2bf(v0);
        xpbf[(size_t)grow * HID + col0 + wc * 32 + 16 + lrow] = f2bf(v1);
      }
      float ps = v0 * as0 + v1 * as1;
      float pd = v0 * ad0 + v1 * ad1;
      #pragma unroll
      for (int off = 1; off < 16; off <<= 1) {
        ps += __shfl_xor(ps, off);
        pd += __shfl_xor(pd, off);
      }
      if (lrow == 0 && grow < M) {
        asrc[grow * HEADS + head] = ps;
        adst[grow * HEADS + head] = pd;
      }
    }
  }
}

// ---------------- edge-weight precompute: ewq[j*4+h] = u64 of 4 tc bf16 weights ----
// thread per (j, head); 4-tc inner; coalesced u64 write.
__global__ __launch_bounds__(256) void k_edgew(const int* __restrict__ col,
    const int* __restrict__ row, const float* __restrict__ asrc,
    const float* __restrict__ adst, u64* __restrict__ ewq) {
  int idx = blockIdx.x * 256 + threadIdx.x;       // NE*HEADS exactly
  int j = idx >> 2, h = idx & 3;
  int c = col[j], r = row[j];
  u64 w = 0;
  #pragma unroll
  for (int tc = 0; tc < TC; tc++) {
    float ev = asrc[((size_t)tc * NN + c) * HEADS + h]
             + adst[((size_t)tc * NN + r) * HEADS + h];
    ev = (ev > 0.f) ? ev : 0.2f * ev;
    w |= ((u64)f2bf(__expf(fminf(ev, 80.f)))) << (tc * 16);
  }
  ewq[idx] = w;
}

// ---------------- GAT aggregation + residual + LayerNorm + ReLU (TC-FUSED) ----------------
// one wave per NODE, all TC timesteps together: edge structure (col + head-weights)
// preloaded once per 16-edge tile; 3 broadcasts per edge serve all 4 tc.
__global__ __launch_bounds__(256) void k_aggr(const u16* __restrict__ xpbf,
    u16* __restrict__ hbf, const float* __restrict__ asrc,
    const float* __restrict__ adst, const u64* __restrict__ ewq,
    const int* __restrict__ rowptr, const int* __restrict__ col,
    const float* __restrict__ bias, const float* __restrict__ lng,
    const float* __restrict__ lnb) {
  int wid = threadIdx.x >> 6, lane = threadIdx.x & 63;
  int node = blockIdx.x * 4 + wid;                 // 0 .. NN
  int hh = lane >> 4, lrow = lane & 15;
  int c0 = lane * 2;
  float bi0 = bias[c0], bi1 = bias[c0 + 1];
  float g0 = lng[c0], g1 = lng[c0 + 1];
  float lb0 = lnb[c0], lb1 = lnb[c0 + 1];
  float den[TC], p0[TC], p1[TC];
  u32 hv[TC];
  #pragma unroll
  for (int tc = 0; tc < TC; tc++) {
    size_t n = (size_t)tc * NN + node;
    float ad = adst[n * HEADS + hh];
    float e0 = asrc[n * HEADS + hh] + ad;          // self-loop (fp32 weight)
    e0 = (e0 > 0.f) ? e0 : 0.2f * e0;
    float w0 = __expf(fminf(e0, 80.f));
    u32 xv = ((const u32*)(xpbf + n * HID))[lane];
    den[tc] = w0;
    p0[tc] = w0 * bf2f((u16)(xv & 0xffff));
    p1[tc] = w0 * bf2f((u16)(xv >> 16));
    hv[tc] = *(const u32*)(hbf + n * HID + c0);
  }
  int rs = rowptr[node], re = rowptr[node + 1];
  for (int tile = rs; tile < re; tile += 16) {
    int cnt = re - tile; if (cnt > 16) cnt = 16;
    int e = tile + lrow;
    int cl = 0; u32 wlo = 0, whi = 0;
    if (e < re) {
      cl = col[e];                                 // same in all 4 head groups
      u64 wq = ewq[(size_t)e * HEADS + hh];        // this head's 4-tc weights
      wlo = (u32)wq; whi = (u32)(wq >> 32);
    }
    for (int k = 0; k < cnt; k++) {
      int sk = __shfl(cl, k, 16);
      u32 wl = (u32)__shfl((int)wlo, k, 16);
      u32 wh = (u32)__shfl((int)whi, k, 16);
      float w_[TC] = { bf2f((u16)(wl & 0xffff)), bf2f((u16)(wl >> 16)),
                       bf2f((u16)(wh & 0xffff)), bf2f((u16)(wh >> 16)) };
      #pragma unroll
      for (int tc = 0; tc < TC; tc++) {
        u32 x = ((const u32*)(xpbf + ((size_t)tc * NN + sk) * HID))[lane];
        den[tc] += w_[tc];
        p0[tc] = fmaf(w_[tc], bf2f((u16)(x & 0xffff)), p0[tc]);
        p1[tc] = fmaf(w_[tc], bf2f((u16)(x >> 16)), p1[tc]);
      }
    }
  }
  #pragma unroll
  for (int tc = 0; tc < TC; tc++) {
    size_t hoff = ((size_t)tc * NN + node) * HID + c0;
    float inv = 1.f / (den[tc] + 1e-16f);
    float o0 = p0[tc] * inv + bi0 + bf2f((u16)(hv[tc] & 0xffff));
    float o1 = p1[tc] * inv + bi1 + bf2f((u16)(hv[tc] >> 16));
    float s2 = o0 + o1;
    #pragma unroll
    for (int off = 32; off; off >>= 1) s2 += __shfl_xor(s2, off);
    float mu = s2 * (1.f / HID);
    float d0 = o0 - mu, d1 = o1 - mu;
    float v2 = d0 * d0 + d1 * d1;
    #pragma unroll
    for (int off = 32; off; off >>= 1) v2 += __shfl_xor(v2, off);
    float rstd = rsqrtf(v2 * (1.f / HID) + 1e-5f);
    o0 = fmaxf(g0 * d0 * rstd + lb0, 0.f);
    o1 = fmaxf(g1 * d1 * rstd + lb1, 0.f);
    *(u32*)(hbf + hoff) = (u32)f2bf(o0) | ((u32)f2bf(o1) << 16);
  }
}

// ---------------- LSTM GEMM + fused gate epilogue (register-transpose, no zs LDS) ----
__device__ __forceinline__ void lstm_body(const u16* __restrict__ A0,
    const u16* __restrict__ A1, const u16* __restrict__ Bt,
    const float* __restrict__ bs, float* __restrict__ cst,
    u16* __restrict__ hout, char* smem, int bx, int by) {
  u16 (*As)[TBK + 8] = (u16(*)[TBK + 8])smem;
  u16 (*Bs)[TBK + 8] = (u16(*)[TBK + 8])(smem + TBM * (TBK + 8) * 2);
  int tid = threadIdx.x;
  int wid = tid >> 6, lane = tid & 63;
  int wr = wid >> 1, wc = wid & 1;
  int lrow = lane & 15, lgrp = lane >> 4;
  int row0 = bx * TBM, col0 = by * TBN;
  floatx4 acc[4][2] = {};
  for (int k0 = 0; k0 < 256; k0 += TBK) {
    const u16* Ap = (k0 < 128) ? A0 : A1;
    int kb = k0 & 127;
    #pragma unroll
    for (int i = 0; i < 4; i++) {
      int idx = tid + i * 256;
      int r = idx >> 3, g = idx & 7;
      int gr = row0 + r;
      short8 v = {};
      if (gr < NN) v = *(const short8*)(Ap + (size_t)gr * 128 + kb + g * 8);
      *(short8*)&As[r][g * 8] = v;
    }
    #pragma unroll
    for (int i = 0; i < 2; i++) {
      int idx = tid + i * 256;
      int r = idx >> 3, g = idx & 7;
      *(short8*)&Bs[r][g * 8] = *(const short8*)(Bt + (size_t)(col0 + r) * 256 + k0 + g * 8);
    }
    __syncthreads();
    #pragma unroll
    for (int kk = 0; kk < TBK; kk += 32) {
      short8 bfr[2];
      #pragma unroll
      for (int n = 0; n < 2; n++)
        bfr[n] = *(const short8*)&Bs[wc * 32 + n * 16 + lrow][kk + lgrp * 8];
      #pragma unroll
      for (int m = 0; m < 4; m++) {
        short8 af = *(const short8*)&As[wr * 64 + m * 16 + lrow][kk + lgrp * 8];
        acc[m][0] = __builtin_amdgcn_mfma_f32_16x16x32_bf16(af, bfr[0], acc[m][0], 0, 0, 0);
        acc[m][1] = __builtin_amdgcn_mfma_f32_16x16x32_bf16(af, bfr[1], acc[m][1], 0, 0, 0);
      }
    }
    __syncthreads();
  }
  // gate epilogue: exact in-register 4x4 transpose within 4-lane groups.
  // after transpose lane sub-index s holds gates g=0..3 (b0..b3) for row offset s.
  int q = lrow >> 2, s = lrow & 3;
  bool odd_s = (lane & 1), hi_s = (lane & 2);
  int ch[2]; float4 bsv[2];
  #pragma unroll
  for (int n = 0; n < 2; n++) {
    ch[n] = by * 16 + wc * 8 + n * 4 + q;
    bsv[n] = *(const float4*)&bs[4 * ch[n]];
  }
  #pragma unroll
  for (int m = 0; m < 4; m++) {
    int grow = row0 + wr * 64 + m * 16 + lgrp * 4 + s;
    bool ok = grow < NN;
    #pragma unroll
    for (int n = 0; n < 2; n++) {
      float a0 = acc[m][n][0], a1 = acc[m][n][1], a2 = acc[m][n][2], a3 = acc[m][n][3];
      float e0 = __shfl_xor(a1, 1), e1 = __shfl_xor(a0, 1);
      float e2 = __shfl_xor(a3, 1), e3 = __shfl_xor(a2, 1);
      float t0 = odd_s ? e0 : a0;
      float t1 = odd_s ? a1 : e1;
      float t2 = odd_s ? e2 : a2;
      float t3 = odd_s ? a3 : e3;
      float f0 = __shfl_xor(t2, 2), f2 = __shfl_xor(t0, 2);
      float f1 = __shfl_xor(t3, 2), f3 = __shfl_xor(t1, 2);
      float b0 = hi_s ? f0 : t0;
      float b1 = hi_s ? f1 : t1;
      float b2 = hi_s ? t2 : f2;
      float b3 = hi_s ? t3 : f3;
      if (ok) {
        size_t gi = (size_t)grow * HID + ch[n];
        float ii = b0 + bsv[n].x;
        float ff = b1 + bsv[n].y;
        float gg = b2 + bsv[n].z;
        float oo = b3 + bsv[n].w;
        float si = 1.f / (1.f + __expf(-ii));
        float sf = 1.f / (1.f + __expf(-ff));
        float so = 1.f / (1.f + __expf(-oo));
        float tg = tanhf(gg);
        float cn = sf * cst[gi] + si * tg;
        cst[gi] = cn;
        hout[gi] = f2bf(so * tanhf(cn));
      }
    }
  }
}

__global__ __launch_bounds__(256) void k_lstm1(const u16* __restrict__ A0,
    const u16* __restrict__ A1, const u16* __restrict__ Bt,
    const float* __restrict__ bs, float* __restrict__ cst, u16* __restrict__ hout) {
  __shared__ __align__(16) char smem[27648];
  lstm_body(A0, A1, Bt, bs, cst, hout, smem, blockIdx.x, blockIdx.y);
}

// merged: z==0 -> cell1(t), z==1 -> cell0(t+1) — independent jobs
__global__ __launch_bounds__(256) void k_lstm2(
    const u16* __restrict__ A0a, const u16* __restrict__ A1a, const u16* __restrict__ Bta,
    const float* __restrict__ bsa, float* __restrict__ csta, u16* __restrict__ houta,
    const u16* __restrict__ A0b, const u16* __restrict__ A1b, const u16* __restrict__ Btb,
    const float* __restrict__ bsb, float* __restrict__ cstb, u16* __restrict__ houtb) {
  __shared__ __align__(16) char smem[27648];
  if (blockIdx.z == 0) lstm_body(A0a, A1a, Bta, bsa, csta, houta, smem, blockIdx.x, blockIdx.y);
  else                 lstm_body(A0b, A1b, Btb, bsb, cstb, houtb, smem, blockIdx.x, blockIdx.y);
}

// ---------------- output MLP: relu(h1@W1+b1)@W2+b2 ----------------
__global__ __launch_bounds__(64) void k_mlp(const u16* __restrict__ h1,
    const float* __restrict__ W1, const float* __restrict__ b1,
    const float* __restrict__ W2, const float* __restrict__ b2,
    float* __restrict__ out) {
  int n = blockIdx.x, j = threadIdx.x;
  const u16* hr = h1 + (size_t)n * HID;
  float acc = b1[j];
  #pragma unroll 8
  for (int k = 0; k < HID; k++) acc = fmaf(bf2f(hr[k]), W1[(size_t)k * 64 + j], acc);
  acc = fmaxf(acc, 0.f);
  float p = acc * W2[j];
  #pragma unroll
  for (int off = 32; off; off >>= 1) p += __shfl_xor(p, off);
  if (j == 0) out[n] = p + b2[0];
}

extern "C" void kernel_launch(void* const* d_in, const int* in_sizes, int n_in,
                              void* d_out, int out_size, void* d_ws, size_t ws_size,
                              hipStream_t stream) {
  const float* xs    = (const float*)d_in[0];
  const float* xd    = (const float*)d_in[1];
  const int*   ei    = (const int*)d_in[2];
  const float* projW = (const float*)d_in[3];
  const float* projb = (const float*)d_in[4];
  const float* gatW  = (const float*)d_in[5];
  const float* attS  = (const float*)d_in[6];
  const float* attD  = (const float*)d_in[7];
  const float* gatb  = (const float*)d_in[8];
  const float* lng   = (const float*)d_in[9];
  const float* lnb   = (const float*)d_in[10];
  const float* Wih0  = (const float*)d_in[11];
  const float* Whh0  = (const float*)d_in[12];
  const float* bih0  = (const float*)d_in[13];
  const float* bhh0  = (const float*)d_in[14];
  const float* Wih1  = (const float*)d_in[15];
  const float* Whh1  = (const float*)d_in[16];
  const float* bih1  = (const float*)d_in[17];
  const float* bhh1  = (const float*)d_in[18];
  const float* oW1   = (const float*)d_in[19];
  const float* ob1   = (const float*)d_in[20];
  const float* oW2   = (const float*)d_in[21];
  const float* ob2   = (const float*)d_in[22];
  float* out = (float*)d_out;

  // -------- workspace layout (~87 MB) --------
  char* w = (char*)d_ws;
  size_t off = 0;
  auto alloc = [&](size_t bytes) { void* p = w + off; off += (bytes + 255) & ~(size_t)255; return p; };
  u16*   hbf   = (u16*)  alloc((size_t)TC * NN * HID * 2);   // bf16 h (GEMM A + residual)
  u16*   xpbf  = (u16*)  alloc((size_t)TC * NN * HID * 2);   // bf16 xp
  float* asrc  = (float*)alloc((size_t)TC * NN * HEADS * 4);
  float* adst  = (float*)alloc((size_t)TC * NN * HEADS * 4);
  u64*   ewq   = (u64*)  alloc((size_t)NE * HEADS * 8);      // 10.2 MB [j][h] -> 4-tc bf16
  float* c01   = (float*)alloc((size_t)2 * NN * HID * 4);    // c0,c1
  float* c0 = c01, *c1 = c01 + (size_t)NN * HID;
  u16*   h0p   = (u16*)  alloc((size_t)2 * NN * HID * 2);    // h0 ping-pong
  u16*   h1p   = (u16*)  alloc((size_t)2 * NN * HID * 2);    // h1 ping-pong
  u16*   h0buf[2] = { h0p, h0p + (size_t)NN * HID };
  u16*   h1buf[2] = { h1p, h1p + (size_t)NN * HID };
  u16*   Wc0bf = (u16*)alloc((size_t)512 * 256 * 2);
  u16*   Wc1bf = (u16*)alloc((size_t)512 * 256 * 2);
  float* bs01  = (float*)alloc((size_t)1024 * 4);
  float* bs0 = bs01, *bs1 = bs01 + 512;
  u16*   gatWbf= (u16*)alloc((size_t)NL * 128 * 128 * 2);
  int* cnt    = (int*)alloc((size_t)NN * 4);
  int* rowptr = (int*)alloc((size_t)(NN + 1) * 4);
  int* cursor = (int*)alloc((size_t)NN * 4);
  int* col    = (int*)alloc((size_t)NE * 4);
  int* rowi   = (int*)alloc((size_t)NE * 4);

  const int* esrc = ei;
  const int* edst = ei + NE;

  // -------- CSR (edge_index identical across t and layers) --------
  hipMemsetAsync(cnt, 0, (size_t)NN * 4, stream);
  k_count<<<(NE + 255) / 256, 256, 0, stream>>>(edst, cnt);
  k_scan<<<1, 1024, 0, stream>>>(cnt, rowptr, cursor);
  k_fill<<<(NE + 255) / 256, 256, 0, stream>>>(esrc, edst, cursor, col, rowi);

  // -------- weight/bias prep + state init --------
  k_prepw_lstm<<<(512 * 256) / 256, 256, 0, stream>>>(Wih0, Whh0, Wc0bf);
  k_prepw_lstm<<<(512 * 256) / 256, 256, 0, stream>>>(Wih1, Whh1, Wc1bf);
  k_prepb<<<2, 512, 0, stream>>>(bih0, bhh0, bih1, bhh1, bs01);
  k_prepw_gat<<<(NL * 128 * 128) / 256, 256, 0, stream>>>(gatW, gatWbf);
  hipMemsetAsync(c01, 0, (size_t)2 * NN * HID * 4, stream);
  hipMemsetAsync(h0buf[0], 0, (size_t)NN * HID * 2, stream);
  hipMemsetAsync(h1buf[0], 0, (size_t)NN * HID * 2, stream);

  const int gx  = (NN + TBM - 1) / TBM;             // 157
  const int gx2 = (TC * NN + TBM - 1) / TBM;        // 625

  auto gnn_chunk = [&](int tcb) {
    k_proj<<<dim3(NN / 16, TC), 256, 0, stream>>>(
        xs, xd + (size_t)(tcb * TC) * NN * DDIM, projW, projb, hbf);
    for (int l = 0; l < NL; l++) {
      k_bgemm_gat<<<dim3(gx2, 2), 256, 0, stream>>>(
          hbf, gatWbf + (size_t)l * 128 * 128,
          attS + l * HEADS * DPH, attD + l * HEADS * DPH,
          xpbf, asrc, adst, TC * NN);
      k_edgew<<<(NE * HEADS) / 256, 256, 0, stream>>>(col, rowi, asrc, adst, ewq);
      k_aggr<<<NN / 4, 256, 0, stream>>>(
          xpbf, hbf, asrc, adst, ewq, rowptr, col, gatb + (size_t)l * HID,
          lng + (size_t)l * HID, lnb + (size_t)l * HID);
    }
  };
  // merged LSTM step: cell1(t) + cell0(t+1)  [independent; buffer audit in journal]
  auto lstm_merged = [&](int t) {
    int pi = t & 1;
    int s1 = (t + 1) & (TC - 1);                   // hbf slot of t+1 within its chunk
    k_lstm2<<<dim3(gx, 8, 2), 256, 0, stream>>>(
        h0buf[pi ^ 1], h1buf[pi], Wc1bf, bs1, c1, h1buf[pi ^ 1],
        hbf + (size_t)s1 * NN * HID, h0buf[pi ^ 1], Wc0bf, bs0, c0, h0buf[pi]);
  };

  // -------- pipeline: GNN chunks + dependency-merged LSTM chain --------
  gnn_chunk(0);
  k_lstm1<<<dim3(gx, 8), 256, 0, stream>>>(hbf, h0buf[0], Wc0bf, bs0, c0, h0buf[1]);  // cell0(t=0)
  lstm_merged(0); lstm_merged(1); lstm_merged(2);
  for (int tcb = 1; tcb < TT / TC; tcb++) {
    gnn_chunk(tcb);
    lstm_merged(4 * tcb - 1);
    lstm_merged(4 * tcb);
    lstm_merged(4 * tcb + 1);
    if (tcb < TT / TC - 1) lstm_merged(4 * tcb + 2);
    else {
      lstm_merged(4 * tcb + 2);                    // t=22
      // final cell1(t=23): reads h0buf[0], h1buf[1] -> h1buf[0]
      k_lstm1<<<dim3(gx, 8), 256, 0, stream>>>(h0buf[0], h1buf[1], Wc1bf, bs1, c1, h1buf[0]);
    }
  }

  // TT even -> final h1 lives in h1buf[0]
  k_mlp<<<NN, 64, 0, stream>>>(h1buf[0], oW1, ob1, oW2, ob2, out);
}